// Round 18
// baseline (403.035 us; speedup 1.0000x reference)
//
#include <hip/hip_runtime.h>

typedef short s16x8 __attribute__((ext_vector_type(8)));
typedef float f32x4 __attribute__((ext_vector_type(4)));

#define CPAD 16  // counters padded to one per 64B line

static __device__ __forceinline__ unsigned short f2bf(float f) {
  unsigned u = __float_as_uint(f);
  u += 0x7fff + ((u >> 16) & 1);  // round-to-nearest-even
  return (unsigned short)(u >> 16);
}
static __device__ __forceinline__ float bf2f(unsigned short h) {
  return __uint_as_float(((unsigned)h) << 16);
}

// ---------------- CSR build ----------------

static __global__ void k_init(int* cntTp, int* cntEp, int n) {
  int i = blockIdx.x * blockDim.x + threadIdx.x;
  if (i < n) { cntTp[(size_t)i * CPAD] = 0; cntEp[(size_t)i * CPAD] = 0; }
}

static __global__ void k_compact(const int* __restrict__ cntTp, const int* __restrict__ cntEp,
                                 int* __restrict__ cntT, int* __restrict__ cntE, int n) {
  int i = blockIdx.x * blockDim.x + threadIdx.x;
  if (i < n) { cntT[i] = cntTp[(size_t)i * CPAD]; cntE[i] = cntEp[(size_t)i * CPAD]; }
}

// 3-phase exclusive scan over both count arrays (grid.y selects array)
static __global__ __launch_bounds__(256) void k_scanA(
    const int* __restrict__ cntT, const int* __restrict__ cntE,
    int* __restrict__ bsum, int n, int nb) {
  const int* cnt = blockIdx.y ? cntE : cntT;
  int tid = threadIdx.x;
  int base = blockIdx.x * 1024 + tid * 4;
  int s = 0;
#pragma unroll
  for (int q = 0; q < 4; ++q) { int i = base + q; if (i < n) s += cnt[i]; }
  __shared__ int red[256];
  red[tid] = s;
  __syncthreads();
  for (int off = 128; off > 0; off >>= 1) {
    if (tid < off) red[tid] += red[tid + off];
    __syncthreads();
  }
  if (tid == 0) bsum[blockIdx.y * nb + blockIdx.x] = red[0];
}

static __global__ void k_scanB(int* bsum, int* ptrT, int* ptrE, int nb, int n) {
  int a = threadIdx.x;
  if (a > 1) return;
  int* bs = bsum + a * nb;
  int run = 0;
  for (int i = 0; i < nb; ++i) { int c = bs[i]; bs[i] = run; run += c; }
  (a ? ptrE : ptrT)[n] = run;
}

static __global__ __launch_bounds__(256) void k_scanC(
    const int* __restrict__ cntT, const int* __restrict__ cntE,
    const int* __restrict__ bsum, int* __restrict__ ptrT, int* __restrict__ ptrE,
    int n, int nb) {
  const int* cnt = blockIdx.y ? cntE : cntT;
  int* ptr = blockIdx.y ? ptrE : ptrT;
  int tid = threadIdx.x;
  int pre = bsum[blockIdx.y * nb + blockIdx.x];
  int base = blockIdx.x * 1024 + tid * 4;
  int v[4];
  int s = 0;
#pragma unroll
  for (int q = 0; q < 4; ++q) { int i = base + q; v[q] = (i < n) ? cnt[i] : 0; s += v[q]; }
  __shared__ int red[256];
  red[tid] = s;
  __syncthreads();
  for (int off = 1; off < 256; off <<= 1) {
    int t = (tid >= off) ? red[tid - off] : 0;
    __syncthreads();
    red[tid] += t;
    __syncthreads();
  }
  int run = pre + (tid ? red[tid - 1] : 0);
#pragma unroll
  for (int q = 0; q < 4; ++q) {
    int i = base + q;
    if (i < n) ptr[i] = run;
    run += v[q];
  }
}

static __global__ void k_dinvT(const int* __restrict__ cntT, float* __restrict__ dinvT, int n) {
  int i = blockIdx.x * blockDim.x + threadIdx.x;
  if (i < n) dinvT[i] = rsqrtf((float)cntT[i] + 1.0f);
}

// atomic-free fill: slot = ptr[col] + rank; 2 edges/thread
static __global__ void k_fill(const int* __restrict__ trow, const int* __restrict__ tcol,
                              const int* __restrict__ erow, const int* __restrict__ ecol,
                              const float* __restrict__ ew, const float* __restrict__ dinvT,
                              const int* __restrict__ ptrT, const int* __restrict__ ptrE,
                              const int* __restrict__ rankT, const int* __restrict__ rankE,
                              int2* __restrict__ srcwT, int2* __restrict__ srcwE, int E) {
  int base = (blockIdx.x * blockDim.x + threadIdx.x) * 2;
  if (base + 1 < E) {
    int2 tr = *(const int2*)&trow[base];
    int2 tc = *(const int2*)&tcol[base];
    int2 er = *(const int2*)&erow[base];
    int2 ec = *(const int2*)&ecol[base];
    float2 w = *(const float2*)&ew[base];
    int2 rt = *(const int2*)&rankT[base];
    int2 re = *(const int2*)&rankE[base];
    int2 p;
    p.x = tr.x; p.y = __float_as_int(dinvT[tr.x]); srcwT[ptrT[tc.x] + rt.x] = p;
    p.x = tr.y; p.y = __float_as_int(dinvT[tr.y]); srcwT[ptrT[tc.y] + rt.y] = p;
    p.x = er.x; p.y = __float_as_int(w.x); srcwE[ptrE[ec.x] + re.x] = p;
    p.x = er.y; p.y = __float_as_int(w.y); srcwE[ptrE[ec.y] + re.y] = p;
  } else if (base < E) {
    int2 p;
    p.x = trow[base]; p.y = __float_as_int(dinvT[trow[base]]);
    srcwT[ptrT[tcol[base]] + rankT[base]] = p;
    p.x = erow[base]; p.y = __float_as_int(ew[base]);
    srcwE[ptrE[ecol[base]] + rankE[base]] = p;
  }
}

static __global__ void k_dinv2E(const int2* __restrict__ srcwE, const int* __restrict__ ptrE,
                                float* __restrict__ dinvE, int n) {
  int i = blockIdx.x * blockDim.x + threadIdx.x;
  if (i >= n) return;
  float s = 1.0f;  // self loop
  int e = ptrE[i + 1];
  for (int j = ptrE[i]; j < e; ++j) s += __int_as_float(srcwE[j].y);
  dinvE[i] = rsqrtf(s);
}

static __global__ void k_wmulE(int2* __restrict__ srcwE, const float* __restrict__ dinvE, int E) {
  int base = (blockIdx.x * blockDim.x + threadIdx.x) * 2;
  if (base + 1 < E) {
    int4 q = *(const int4*)&srcwE[base];
    q.y = __float_as_int(__int_as_float(q.y) * dinvE[q.x]);
    q.w = __float_as_int(__int_as_float(q.w) * dinvE[q.z]);
    *(int4*)&srcwE[base] = q;
  } else if (base < E) {
    int2 p = srcwE[base];
    p.y = __float_as_int(__int_as_float(p.y) * dinvE[p.x]);
    srcwE[base] = p;
  }
}

// ---------------- W -> k-tiled transposed bf16 split (linear) ----------------
// Wh/Wl[kt][c][kk]  (kt = k/32, kk = k%32, c = 0..Nc-1)

static __global__ void k_cvtW(const float* __restrict__ W, unsigned short* __restrict__ Wh,
                              unsigned short* __restrict__ Wl, int K, int Nc) {
  int t = blockIdx.x * blockDim.x + threadIdx.x;
  if (t >= K * Nc) return;
  int k = t / Nc, c = t - k * Nc;
  float v = W[t];
  unsigned short hi = f2bf(v);
  size_t o = (size_t)(k >> 5) * (Nc * 32) + (size_t)c * 32 + (k & 31);
  Wh[o] = hi;
  Wl[o] = f2bf(v - bf2f(hi));
}

#define GK 512
#define NKT 16

static __device__ __forceinline__ void cvt8(float4 a, float4 b, s16x8& hi, s16x8& lo) {
  float f[8] = {a.x, a.y, a.z, a.w, b.x, b.y, b.z, b.w};
#pragma unroll
  for (int i = 0; i < 8; ++i) {
    unsigned short h = f2bf(f[i]);
    hi[i] = (short)h;
    lo[i] = (short)f2bf(f[i] - bf2f(h));
  }
}

// ---------------- FUSED: conv1 MFMA GEMM (R8 LDS-free) + k_count ----------------
// Zero LDS so count blocks pack densely (R17's 49KB/block starved them to
// ~3 blocks/CU). GEMM: frozen R8 structure (78 us standalone): A fragments
// straight from global, B from L2-resident linear k-tiled layout, no barriers.

static __global__ __launch_bounds__(256, 2) void k_gemm_count(
    const float* __restrict__ A, const unsigned short* __restrict__ Bh,
    const unsigned short* __restrict__ Bl, float* __restrict__ C, int M, int NG,
    const int* __restrict__ tcol, const int* __restrict__ ecol,
    int* __restrict__ cntTp, int* __restrict__ cntEp,
    int* __restrict__ rankT, int* __restrict__ rankE, int E) {
  int bid = blockIdx.x;
  if (bid % 5 != 0) {
    // ---- count block: 1 edge/thread, grid-stride ----
    int cb = bid - bid / 5 - 1;
    int ncb = gridDim.x - NG;
    for (int e = cb * 256 + threadIdx.x; e < E; e += ncb * 256) {
      rankT[e] = atomicAdd(&cntTp[(size_t)tcol[e] * CPAD], 1);
      rankE[e] = atomicAdd(&cntEp[(size_t)ecol[e] * CPAD], 1);
    }
    return;
  }
  // ---- GEMM block (frozen R8 body) ----
  int tid = threadIdx.x;
  int lane = tid & 63, wid = tid >> 6;
  int wr = wid >> 1, wc = wid & 1;        // wave = 32 rows x 64 cols
  int l15 = lane & 15, l4 = lane >> 4;
  int brow = (bid / 5) * 64;
  f32x4 acc[2][4] = {};

  const float* arow[2];
#pragma unroll
  for (int m = 0; m < 2; ++m) {
    int r = brow + wr * 32 + m * 16 + l15;
    arow[m] = &A[(size_t)min(r, M - 1) * GK + l4 * 8];
  }
  size_t boff = (size_t)(wc * 64 + l15) * 32 + l4 * 8;  // + n*512 + kt*4096

#pragma unroll
  for (int kt = 0; kt < NKT; ++kt) {
    s16x8 afh[2], afl[2];
#pragma unroll
    for (int m = 0; m < 2; ++m) {
      float4 a0 = *(const float4*)(arow[m] + kt * 32);
      float4 a1 = *(const float4*)(arow[m] + kt * 32 + 4);
      cvt8(a0, a1, afh[m], afl[m]);
    }
    s16x8 bh[4], bl[4];
#pragma unroll
    for (int n = 0; n < 4; ++n) {
      size_t o = (size_t)kt * 4096 + boff + n * 512;
      bh[n] = *(const s16x8*)&Bh[o];
      bl[n] = *(const s16x8*)&Bl[o];
    }
#pragma unroll
    for (int m = 0; m < 2; ++m)
#pragma unroll
      for (int n = 0; n < 4; ++n) {
        acc[m][n] = __builtin_amdgcn_mfma_f32_16x16x32_bf16(afh[m], bh[n], acc[m][n], 0, 0, 0);
        acc[m][n] = __builtin_amdgcn_mfma_f32_16x16x32_bf16(afl[m], bh[n], acc[m][n], 0, 0, 0);
        acc[m][n] = __builtin_amdgcn_mfma_f32_16x16x32_bf16(afh[m], bl[n], acc[m][n], 0, 0, 0);
      }
  }

#pragma unroll
  for (int m = 0; m < 2; ++m) {
    int rbase = brow + wr * 32 + m * 16 + l4 * 4;
#pragma unroll
    for (int n = 0; n < 4; ++n) {
      int c = wc * 64 + n * 16 + l15;
#pragma unroll
      for (int j = 0; j < 4; ++j) {
        int r = rbase + j;
        if (r < M) C[(size_t)r * 128 + c] = acc[m][n][j];
      }
    }
  }
}

// ---------------- MFMA split-bf16 GEMM (conv2): C[M][64] = A[M][128] @ B ----------------

static __global__ __launch_bounds__(256, 2) void k_gemm_mfma64(
    const float* __restrict__ A, const unsigned short* __restrict__ Bh,
    const unsigned short* __restrict__ Bl, float* __restrict__ C, int M) {
  int tid = threadIdx.x;
  int lane = tid & 63, wid = tid >> 6;
  int wr = wid >> 1, wc = wid & 1;
  int l15 = lane & 15, l4 = lane >> 4;
  int brow = blockIdx.x * 64;
  f32x4 acc[2][2] = {};

  const float* arow[2];
#pragma unroll
  for (int m = 0; m < 2; ++m) {
    int r = brow + wr * 32 + m * 16 + l15;
    arow[m] = &A[(size_t)min(r, M - 1) * 128 + l4 * 8];
  }
  size_t boff = (size_t)(wc * 32 + l15) * 32 + l4 * 8;

#pragma unroll
  for (int kt = 0; kt < 4; ++kt) {
    s16x8 afh[2], afl[2];
#pragma unroll
    for (int m = 0; m < 2; ++m) {
      float4 a0 = *(const float4*)(arow[m] + kt * 32);
      float4 a1 = *(const float4*)(arow[m] + kt * 32 + 4);
      cvt8(a0, a1, afh[m], afl[m]);
    }
    s16x8 bh[2], bl[2];
#pragma unroll
    for (int n = 0; n < 2; ++n) {
      size_t o = (size_t)kt * 2048 + boff + n * 512;
      bh[n] = *(const s16x8*)&Bh[o];
      bl[n] = *(const s16x8*)&Bl[o];
    }
#pragma unroll
    for (int m = 0; m < 2; ++m)
#pragma unroll
      for (int n = 0; n < 2; ++n) {
        acc[m][n] = __builtin_amdgcn_mfma_f32_16x16x32_bf16(afh[m], bh[n], acc[m][n], 0, 0, 0);
        acc[m][n] = __builtin_amdgcn_mfma_f32_16x16x32_bf16(afl[m], bh[n], acc[m][n], 0, 0, 0);
        acc[m][n] = __builtin_amdgcn_mfma_f32_16x16x32_bf16(afh[m], bl[n], acc[m][n], 0, 0, 0);
      }
  }

#pragma unroll
  for (int m = 0; m < 2; ++m) {
    int rbase = brow + wr * 32 + m * 16 + l4 * 4;
#pragma unroll
    for (int n = 0; n < 2; ++n) {
      int c = wc * 32 + n * 16 + l15;
#pragma unroll
      for (int j = 0; j < 4; ++j) {
        int r = rbase + j;
        if (r < M) C[(size_t)r * 64 + c] = acc[m][n][j];
      }
    }
  }
}

// ---------------- gather-aggregate (CSR with folded weights) ----------------

template <int F, bool RELU>
static __global__ __launch_bounds__(256) void k_gather4(
    const float* __restrict__ H, const int* __restrict__ rowptr,
    const int2* __restrict__ srcw, const float* __restrict__ dinv,
    const float* __restrict__ Hpre, const float* __restrict__ bias,
    float* __restrict__ out, int n) {
  const int L = F / 4;
  int node = blockIdx.x * (256 / L) + threadIdx.x / L;
  if (node >= n) return;
  int f4 = (threadIdx.x % L) * 4;
  float d = dinv[node];
  float4 hp = *(const float4*)&Hpre[(size_t)node * F + f4];
  float ax = hp.x * d, ay = hp.y * d, az = hp.z * d, aw = hp.w * d;
  int j = rowptr[node], e = rowptr[node + 1];
  for (; j + 1 < e; j += 2) {
    int2 a = srcw[j], b = srcw[j + 1];
    float w0 = __int_as_float(a.y);
    float w1 = __int_as_float(b.y);
    float4 v0 = *(const float4*)&H[(size_t)a.x * F + f4];
    float4 v1 = *(const float4*)&H[(size_t)b.x * F + f4];
    ax += v0.x * w0 + v1.x * w1;
    ay += v0.y * w0 + v1.y * w1;
    az += v0.z * w0 + v1.z * w1;
    aw += v0.w * w0 + v1.w * w1;
  }
  if (j < e) {
    int2 a = srcw[j];
    float wj = __int_as_float(a.y);
    float4 v = *(const float4*)&H[(size_t)a.x * F + f4];
    ax += v.x * wj; ay += v.y * wj; az += v.z * wj; aw += v.w * wj;
  }
  float bx = 0, by = 0, bz = 0, bw = 0;
  if (bias) { float4 bb = *(const float4*)&bias[f4]; bx = bb.x; by = bb.y; bz = bb.z; bw = bb.w; }
  ax = ax * d + bx; ay = ay * d + by; az = az * d + bz; aw = aw * d + bw;
  if (RELU) { ax = fmaxf(ax, 0.f); ay = fmaxf(ay, 0.f); az = fmaxf(az, 0.f); aw = fmaxf(aw, 0.f); }
  float4 o; o.x = ax; o.y = ay; o.z = az; o.w = aw;
  *(float4*)&out[(size_t)node * F + f4] = o;
}

// ---------------- FUSED: gather3 (E-graph, F=64) + link prediction ----------------
// Both depend only on bufC (h2); disjoint outputs -> run as one grid.

static __global__ __launch_bounds__(256) void k_gather_lp(
    const float* __restrict__ H, const int* __restrict__ rowptr,
    const int2* __restrict__ srcw, const float* __restrict__ dinv,
    float* __restrict__ outAgg, int n, int NGa,
    const int* __restrict__ pos, const int* __restrict__ neg,
    float* __restrict__ res, int Elp) {
  int bid = blockIdx.x;
  if (bid < NGa) {
    // ---- gather3 body (F=64, no relu, no bias, Hpre = H) ----
    int node = bid * 16 + threadIdx.x / 16;
    if (node >= n) return;
    int f4 = (threadIdx.x % 16) * 4;
    float d = dinv[node];
    float4 hp = *(const float4*)&H[(size_t)node * 64 + f4];
    float ax = hp.x * d, ay = hp.y * d, az = hp.z * d, aw = hp.w * d;
    int j = rowptr[node], e = rowptr[node + 1];
    for (; j + 1 < e; j += 2) {
      int2 a = srcw[j], b = srcw[j + 1];
      float w0 = __int_as_float(a.y);
      float w1 = __int_as_float(b.y);
      float4 v0 = *(const float4*)&H[(size_t)a.x * 64 + f4];
      float4 v1 = *(const float4*)&H[(size_t)b.x * 64 + f4];
      ax += v0.x * w0 + v1.x * w1;
      ay += v0.y * w0 + v1.y * w1;
      az += v0.z * w0 + v1.z * w1;
      aw += v0.w * w0 + v1.w * w1;
    }
    if (j < e) {
      int2 a = srcw[j];
      float wj = __int_as_float(a.y);
      float4 v = *(const float4*)&H[(size_t)a.x * 64 + f4];
      ax += v.x * wj; ay += v.y * wj; az += v.z * wj; aw += v.w * wj;
    }
    float4 o; o.x = ax * d; o.y = ay * d; o.z = az * d; o.w = aw * d;
    *(float4*)&outAgg[(size_t)node * 64 + f4] = o;
  } else {
    // ---- linkpred body ----
    int t = (bid - NGa) * 256 + threadIdx.x;
    int e = t >> 4, f4 = (t & 15) * 4;
    if (e >= 2 * Elp) return;
    int a, b;
    if (e < Elp) { a = pos[e]; b = pos[Elp + e]; }
    else { int e2 = e - Elp; a = neg[e2]; b = neg[Elp + e2]; }
    float4 va = *(const float4*)&H[(size_t)a * 64 + f4];
    float4 vb = *(const float4*)&H[(size_t)b * 64 + f4];
    float p = va.x * vb.x + va.y * vb.y + va.z * vb.z + va.w * vb.w;
    p += __shfl_xor(p, 1);
    p += __shfl_xor(p, 2);
    p += __shfl_xor(p, 4);
    p += __shfl_xor(p, 8);
    if ((t & 15) == 0) res[e] = p;
  }
}

// ---------------- fused dual-head (64->40 x2) + log-softmax ----------------

static __global__ __launch_bounds__(256) void k_heads(
    const float* __restrict__ H, const float* __restrict__ Wattr,
    const float* __restrict__ battr, const float* __restrict__ Watt,
    const float* __restrict__ batt, float* __restrict__ out_attr,
    float* __restrict__ out_att, int n) {
  __shared__ float Hs[64][65];
  __shared__ float Ws[64][80];
  __shared__ float bs[80];
  __shared__ float Os[64][82];
  int tid = threadIdx.x;
  int node0 = blockIdx.x * 64;
  for (int i = tid; i < 1024; i += 256) {
    int r = i >> 4, c4 = (i & 15) * 4;
    float4 v = (node0 + r < n) ? *(const float4*)&H[(size_t)(node0 + r) * 64 + c4]
                               : make_float4(0.f, 0.f, 0.f, 0.f);
    Hs[r][c4] = v.x; Hs[r][c4 + 1] = v.y; Hs[r][c4 + 2] = v.z; Hs[r][c4 + 3] = v.w;
  }
  for (int i = tid; i < 64 * 40; i += 256) {
    int k = i / 40, j = i - k * 40;
    Ws[k][j] = Wattr[i];
    Ws[k][40 + j] = Watt[i];
  }
  if (tid < 40) { bs[tid] = battr[tid]; bs[40 + tid] = batt[tid]; }
  __syncthreads();

  int r = tid & 63, g = tid >> 6;
  float acc[20];
#pragma unroll
  for (int j = 0; j < 20; ++j) acc[j] = bs[g * 20 + j];
  for (int k = 0; k < 64; ++k) {
    float h = Hs[r][k];
#pragma unroll
    for (int j = 0; j < 20; ++j) acc[j] += h * Ws[k][g * 20 + j];
  }
#pragma unroll
  for (int j = 0; j < 20; ++j) Os[r][g * 20 + j] = acc[j];
  __syncthreads();

  if (tid < 128 && node0 + (tid & 63) < n) {
    int r2 = tid & 63;
    int base = (tid >> 6) * 40;
    float m = -1e30f;
    for (int j = 0; j < 40; ++j) m = fmaxf(m, Os[r2][base + j]);
    float s = 0.f;
    for (int j = 0; j < 40; ++j) s += expf(Os[r2][base + j] - m);
    float ls = logf(s) + m;
    float* o = (tid < 64 ? out_attr : out_att) + (size_t)(node0 + r2) * 40;
    for (int j = 0; j < 40; ++j) o[j] = Os[r2][base + j] - ls;
  }
}

// ---------------- launch ----------------

extern "C" void kernel_launch(void* const* d_in, const int* in_sizes, int n_in,
                              void* d_out, int out_size, void* d_ws, size_t ws_size,
                              hipStream_t stream) {
  const float* x    = (const float*)d_in[0];
  const int*   tp   = (const int*)d_in[1];
  const int*   ei   = (const int*)d_in[2];
  const float* ew   = (const float*)d_in[3];
  const int*   pos  = (const int*)d_in[4];
  const int*   neg  = (const int*)d_in[5];
  const float* W1   = (const float*)d_in[6];
  const float* b1   = (const float*)d_in[7];
  const float* W2   = (const float*)d_in[8];
  const float* b2   = (const float*)d_in[9];
  const float* Wattr= (const float*)d_in[10];
  const float* battr= (const float*)d_in[11];
  const float* Watt = (const float*)d_in[12];
  const float* batt = (const float*)d_in[13];

  const int N   = in_sizes[0] / 512;  // 50000
  const int EMP = in_sizes[1] / 2;    // 800000
  const int ELP = in_sizes[4] / 2;    // 250000
  const int NB  = (N + 1023) / 1024;  // scan blocks per array
  const int NG  = (N + 63) / 64;      // gemm blocks
  const int NGa = (N + 15) / 16;      // gather3 blocks

  // workspace layout (4B units, 16B-aligned regions)
  float* ws = (float*)d_ws;
  float* dinvT = ws;                          // N
  float* dinvE = dinvT + N;                   // N
  int* rowptrT = (int*)(dinvE + N);           // N+1 (+pad)
  int* rowptrE = rowptrT + (N + 4);           // N+1 (+pad)
  int2* srcwT  = (int2*)(rowptrE + (N + 4));  // EMP int2
  int2* srcwE  = srcwT + EMP;                 // EMP int2
  int* bsum    = (int*)(srcwE + EMP);         // 2*NB (+pad)
  unsigned short* W1h = (unsigned short*)(bsum + 128);  // 512*128 bf16 (k-tiled linear)
  unsigned short* W1l = W1h + 512 * 128;
  unsigned short* W2h = W1l + 512 * 128;      // 128*64 bf16 (k-tiled linear)
  unsigned short* W2l = W2h + 128 * 64;
  float* bufA  = (float*)(W2l + 128 * 64);    // N*128
  float* bufB  = bufA + (size_t)N * 128;      // N*128
  float* bufC  = bufB + (size_t)N * 128;      // N*64
  // ranks: DEDICATED region (concurrent with gemm writing bufA)
  int* rankT = (int*)(bufC + (size_t)N * 64); // EMP
  int* rankE = rankT + EMP;                   // EMP
  // overlays (dead before their hosts are written):
  int* cntTp = (int*)bufB;                    // N*CPAD padded counters
  int* cntEp = cntTp + (size_t)N * CPAD;      // N*CPAD
  int* cntT  = cntEp + (size_t)N * CPAD;      // N dense
  int* cntE  = cntT + N;                      // N dense

  float* out_res  = (float*)d_out;
  float* out_attr = out_res + 2 * (size_t)ELP;
  float* out_att  = out_attr + (size_t)N * 40;

  dim3 b256(256);
  int gN = (N + 255) / 256;
  int gE2 = (EMP + 511) / 512;

  // counters zero + W converts (all precede the fused kernel)
  k_init<<<gN, b256, 0, stream>>>(cntTp, cntEp, N);
  k_cvtW<<<(512 * 128 + 255) / 256, b256, 0, stream>>>(W1, W1h, W1l, 512, 128);
  k_cvtW<<<(128 * 64 + 255) / 256, b256, 0, stream>>>(W2, W2h, W2l, 128, 64);

  // FUSED: conv1 GEMM (h1_pre = x @ W1, LDS-free) + k_count (interleaved)
  k_gemm_count<<<NG * 5, b256, 0, stream>>>(x, W1h, W1l, bufA, N, NG,
                                            tp + EMP, ei + EMP, cntTp, cntEp,
                                            rankT, rankE, EMP);

  // CSR build rest
  k_compact<<<gN, b256, 0, stream>>>(cntTp, cntEp, cntT, cntE, N);
  k_dinvT<<<gN, b256, 0, stream>>>(cntT, dinvT, N);
  {
    dim3 gs(NB, 2);
    k_scanA<<<gs, b256, 0, stream>>>(cntT, cntE, bsum, N, NB);
    k_scanB<<<1, 64, 0, stream>>>(bsum, rowptrT, rowptrE, NB, N);
    k_scanC<<<gs, b256, 0, stream>>>(cntT, cntE, bsum, rowptrT, rowptrE, N, NB);
  }
  k_fill<<<gE2, b256, 0, stream>>>(tp, tp + EMP, ei, ei + EMP, ew, dinvT,
                                   rowptrT, rowptrE, rankT, rankE, srcwT, srcwE, EMP);
  k_dinv2E<<<gN, b256, 0, stream>>>(srcwE, rowptrE, dinvE, N);
  k_wmulE<<<(EMP + 511) / 512, b256, 0, stream>>>(srcwE, dinvE, EMP);

  // conv1 aggregate: h = relu(Agg_T(h1_pre) + b1)
  k_gather4<128, true><<<(N + 7) / 8, b256, 0, stream>>>(
      bufA, rowptrT, srcwT, dinvT, bufA, b1, bufB, N);

  // conv2: h2_pre = h @ W2 ; h2 = Agg_T(h2_pre) + b2
  k_gemm_mfma64<<<(N + 63) / 64, b256, 0, stream>>>(bufB, W2h, W2l, bufA, N);
  k_gather4<64, false><<<(N + 15) / 16, b256, 0, stream>>>(
      bufA, rowptrT, srcwT, dinvT, bufA, b2, bufC, N);

  // FUSED: gather3 (agg3 = Agg_E(h2) into bufA) + link prediction (from bufC)
  k_gather_lp<<<NGa + (2 * ELP * 16 + 255) / 256, b256, 0, stream>>>(
      bufC, rowptrE, srcwE, dinvE, bufA, N, NGa, pos, neg, out_res, ELP);

  // fused heads + log-softmax
  k_heads<<<(N + 63) / 64, b256, 0, stream>>>(
      bufA, Wattr, battr, Watt, batt, out_attr, out_att, N);
}

// Round 19
// 383.084 us; speedup vs baseline: 1.0521x; 1.0521x over previous
//
#include <hip/hip_runtime.h>

typedef short s16x8 __attribute__((ext_vector_type(8)));
typedef float f32x4 __attribute__((ext_vector_type(4)));

#define CPAD 16  // counters padded to one per 64B line

static __device__ __forceinline__ unsigned short f2bf(float f) {
  unsigned u = __float_as_uint(f);
  u += 0x7fff + ((u >> 16) & 1);  // round-to-nearest-even
  return (unsigned short)(u >> 16);
}
static __device__ __forceinline__ float bf2f(unsigned short h) {
  return __uint_as_float(((unsigned)h) << 16);
}

// ---------------- CSR build ----------------

static __global__ void k_init(int* cntTp, int* cntEp, int n) {
  int i = blockIdx.x * blockDim.x + threadIdx.x;
  if (i < n) { cntTp[(size_t)i * CPAD] = 0; cntEp[(size_t)i * CPAD] = 0; }
}

static __global__ void k_compact(const int* __restrict__ cntTp, const int* __restrict__ cntEp,
                                 int* __restrict__ cntT, int* __restrict__ cntE, int n) {
  int i = blockIdx.x * blockDim.x + threadIdx.x;
  if (i < n) { cntT[i] = cntTp[(size_t)i * CPAD]; cntE[i] = cntEp[(size_t)i * CPAD]; }
}

// 3-phase exclusive scan over both count arrays (grid.y selects array)
static __global__ __launch_bounds__(256) void k_scanA(
    const int* __restrict__ cntT, const int* __restrict__ cntE,
    int* __restrict__ bsum, int n, int nb) {
  const int* cnt = blockIdx.y ? cntE : cntT;
  int tid = threadIdx.x;
  int base = blockIdx.x * 1024 + tid * 4;
  int s = 0;
#pragma unroll
  for (int q = 0; q < 4; ++q) { int i = base + q; if (i < n) s += cnt[i]; }
  __shared__ int red[256];
  red[tid] = s;
  __syncthreads();
  for (int off = 128; off > 0; off >>= 1) {
    if (tid < off) red[tid] += red[tid + off];
    __syncthreads();
  }
  if (tid == 0) bsum[blockIdx.y * nb + blockIdx.x] = red[0];
}

static __global__ void k_scanB(int* bsum, int* ptrT, int* ptrE, int nb, int n) {
  int a = threadIdx.x;
  if (a > 1) return;
  int* bs = bsum + a * nb;
  int run = 0;
  for (int i = 0; i < nb; ++i) { int c = bs[i]; bs[i] = run; run += c; }
  (a ? ptrE : ptrT)[n] = run;
}

static __global__ __launch_bounds__(256) void k_scanC(
    const int* __restrict__ cntT, const int* __restrict__ cntE,
    const int* __restrict__ bsum, int* __restrict__ ptrT, int* __restrict__ ptrE,
    int n, int nb) {
  const int* cnt = blockIdx.y ? cntE : cntT;
  int* ptr = blockIdx.y ? ptrE : ptrT;
  int tid = threadIdx.x;
  int pre = bsum[blockIdx.y * nb + blockIdx.x];
  int base = blockIdx.x * 1024 + tid * 4;
  int v[4];
  int s = 0;
#pragma unroll
  for (int q = 0; q < 4; ++q) { int i = base + q; v[q] = (i < n) ? cnt[i] : 0; s += v[q]; }
  __shared__ int red[256];
  red[tid] = s;
  __syncthreads();
  for (int off = 1; off < 256; off <<= 1) {
    int t = (tid >= off) ? red[tid - off] : 0;
    __syncthreads();
    red[tid] += t;
    __syncthreads();
  }
  int run = pre + (tid ? red[tid - 1] : 0);
#pragma unroll
  for (int q = 0; q < 4; ++q) {
    int i = base + q;
    if (i < n) ptr[i] = run;
    run += v[q];
  }
}

static __global__ void k_dinvT(const int* __restrict__ cntT, float* __restrict__ dinvT, int n) {
  int i = blockIdx.x * blockDim.x + threadIdx.x;
  if (i < n) dinvT[i] = rsqrtf((float)cntT[i] + 1.0f);
}

// atomic-free fill: slot = ptr[col] + rank; 2 edges/thread
static __global__ void k_fill(const int* __restrict__ trow, const int* __restrict__ tcol,
                              const int* __restrict__ erow, const int* __restrict__ ecol,
                              const float* __restrict__ ew, const float* __restrict__ dinvT,
                              const int* __restrict__ ptrT, const int* __restrict__ ptrE,
                              const int* __restrict__ rankT, const int* __restrict__ rankE,
                              int2* __restrict__ srcwT, int2* __restrict__ srcwE, int E) {
  int base = (blockIdx.x * blockDim.x + threadIdx.x) * 2;
  if (base + 1 < E) {
    int2 tr = *(const int2*)&trow[base];
    int2 tc = *(const int2*)&tcol[base];
    int2 er = *(const int2*)&erow[base];
    int2 ec = *(const int2*)&ecol[base];
    float2 w = *(const float2*)&ew[base];
    int2 rt = *(const int2*)&rankT[base];
    int2 re = *(const int2*)&rankE[base];
    int2 p;
    p.x = tr.x; p.y = __float_as_int(dinvT[tr.x]); srcwT[ptrT[tc.x] + rt.x] = p;
    p.x = tr.y; p.y = __float_as_int(dinvT[tr.y]); srcwT[ptrT[tc.y] + rt.y] = p;
    p.x = er.x; p.y = __float_as_int(w.x); srcwE[ptrE[ec.x] + re.x] = p;
    p.x = er.y; p.y = __float_as_int(w.y); srcwE[ptrE[ec.y] + re.y] = p;
  } else if (base < E) {
    int2 p;
    p.x = trow[base]; p.y = __float_as_int(dinvT[trow[base]]);
    srcwT[ptrT[tcol[base]] + rankT[base]] = p;
    p.x = erow[base]; p.y = __float_as_int(ew[base]);
    srcwE[ptrE[ecol[base]] + rankE[base]] = p;
  }
}

static __global__ void k_dinv2E(const int2* __restrict__ srcwE, const int* __restrict__ ptrE,
                                float* __restrict__ dinvE, int n) {
  int i = blockIdx.x * blockDim.x + threadIdx.x;
  if (i >= n) return;
  float s = 1.0f;  // self loop
  int e = ptrE[i + 1];
  for (int j = ptrE[i]; j < e; ++j) s += __int_as_float(srcwE[j].y);
  dinvE[i] = rsqrtf(s);
}

static __global__ void k_wmulE(int2* __restrict__ srcwE, const float* __restrict__ dinvE, int E) {
  int base = (blockIdx.x * blockDim.x + threadIdx.x) * 2;
  if (base + 1 < E) {
    int4 q = *(const int4*)&srcwE[base];
    q.y = __float_as_int(__int_as_float(q.y) * dinvE[q.x]);
    q.w = __float_as_int(__int_as_float(q.w) * dinvE[q.z]);
    *(int4*)&srcwE[base] = q;
  } else if (base < E) {
    int2 p = srcwE[base];
    p.y = __float_as_int(__int_as_float(p.y) * dinvE[p.x]);
    srcwE[base] = p;
  }
}

// ---------------- W -> k-tiled transposed bf16 split ----------------
// swizzled=0: Wh/Wl[kt][c][kk] (linear, conv2).
// swizzled=1: chunk q stored at q^swz(c), swz(c)=(c&3)^((c>>2)&3) (conv1 LDS image).

static __global__ void k_cvtW(const float* __restrict__ W, unsigned short* __restrict__ Wh,
                              unsigned short* __restrict__ Wl, int K, int Nc, int swizzled) {
  int t = blockIdx.x * blockDim.x + threadIdx.x;
  if (t >= K * Nc) return;
  int k = t / Nc, c = t - k * Nc;
  float v = W[t];
  unsigned short hi = f2bf(v);
  int kk = k & 31;
  if (swizzled) {
    int q = kk >> 3, j = kk & 7;
    int sw = (c & 3) ^ ((c >> 2) & 3);
    kk = ((q ^ sw) << 3) + j;
  }
  size_t o = (size_t)(k >> 5) * (Nc * 32) + (size_t)c * 32 + kk;
  Wh[o] = hi;
  Wl[o] = f2bf(v - bf2f(hi));
}

#define GK 512
#define NKT 16

static __device__ __forceinline__ void cvt8(float4 a, float4 b, s16x8& hi, s16x8& lo) {
  float f[8] = {a.x, a.y, a.z, a.w, b.x, b.y, b.z, b.w};
#pragma unroll
  for (int i = 0; i < 8; ++i) {
    unsigned short h = f2bf(f[i]);
    hi[i] = (short)h;
    lo[i] = (short)f2bf(f[i] - bf2f(h));
  }
}

// ---------------- FUSED: conv1 MFMA GEMM (2-stage glld) + k_count ----------------
// R17 configuration — best measured (384 us total). GEMM blocks (bid%5==0)
// and count blocks share the machine; glld staging keeps the GEMM's VMEM
// fire-and-forget while count blocks stream through spare slots.

static __global__ __launch_bounds__(256, 2) void k_gemm_count(
    const float* __restrict__ A, const unsigned short* __restrict__ Bh,
    const unsigned short* __restrict__ Bl, float* __restrict__ C, int M, int NG,
    const int* __restrict__ tcol, const int* __restrict__ ecol,
    int* __restrict__ cntTp, int* __restrict__ cntEp,
    int* __restrict__ rankT, int* __restrict__ rankE, int E) {
  __shared__ __align__(16) float          AfS[2][2048];   // 8 KB
  __shared__ __align__(16) unsigned short BhS[2][4096];   // 8 KB
  __shared__ __align__(16) unsigned short BlS[2][4096];   // 8 KB
  int bid = blockIdx.x;
  if (bid % 5 != 0) {
    // ---- count block: 1 edge/thread, grid-stride ----
    int cb = bid - bid / 5 - 1;
    int ncb = gridDim.x - NG;
    for (int e = cb * 256 + threadIdx.x; e < E; e += ncb * 256) {
      rankT[e] = atomicAdd(&cntTp[(size_t)tcol[e] * CPAD], 1);
      rankE[e] = atomicAdd(&cntEp[(size_t)ecol[e] * CPAD], 1);
    }
    return;
  }
  // ---- GEMM block ----
  int tid = threadIdx.x;
  int lane = tid & 63, wid = tid >> 6;
  int wr = wid >> 1, wc = wid & 1;        // wave = 32 rows x 64 cols
  int l15 = lane & 15, l4 = lane >> 4;
  int brow = (bid / 5) * 64;
  f32x4 acc[2][4] = {};

  int idx0 = wid * 2, idx1 = wid * 2 + 1;
  int arow0 = idx0 * 8 + (lane >> 3);
  int arow1 = idx1 * 8 + (lane >> 3);
  int achk = ((lane & 7) ^ (lane >> 3)) << 2;
  const float* asrc0 = &A[(size_t)min(brow + arow0, M - 1) * GK + achk];
  const float* asrc1 = &A[(size_t)min(brow + arow1, M - 1) * GK + achk];
  const unsigned short* bhsrc0 = &Bh[idx0 * 512 + lane * 8];
  const unsigned short* bhsrc1 = &Bh[idx1 * 512 + lane * 8];
  const unsigned short* blsrc0 = &Bl[idx0 * 512 + lane * 8];
  const unsigned short* blsrc1 = &Bl[idx1 * 512 + lane * 8];

#define STG(buf, kt)                                                                       \
  do {                                                                                     \
    __builtin_amdgcn_global_load_lds(                                                      \
        (const __attribute__((address_space(1))) void*)(asrc0 + (kt) * 32),                \
        (__attribute__((address_space(3))) void*)&AfS[buf][idx0 * 256], 16, 0, 0);         \
    __builtin_amdgcn_global_load_lds(                                                      \
        (const __attribute__((address_space(1))) void*)(asrc1 + (kt) * 32),                \
        (__attribute__((address_space(3))) void*)&AfS[buf][idx1 * 256], 16, 0, 0);         \
    __builtin_amdgcn_global_load_lds(                                                      \
        (const __attribute__((address_space(1))) void*)(bhsrc0 + (size_t)(kt) * 4096),     \
        (__attribute__((address_space(3))) void*)&BhS[buf][idx0 * 512], 16, 0, 0);         \
    __builtin_amdgcn_global_load_lds(                                                      \
        (const __attribute__((address_space(1))) void*)(bhsrc1 + (size_t)(kt) * 4096),     \
        (__attribute__((address_space(3))) void*)&BhS[buf][idx1 * 512], 16, 0, 0);         \
    __builtin_amdgcn_global_load_lds(                                                      \
        (const __attribute__((address_space(1))) void*)(blsrc0 + (size_t)(kt) * 4096),     \
        (__attribute__((address_space(3))) void*)&BlS[buf][idx0 * 512], 16, 0, 0);         \
    __builtin_amdgcn_global_load_lds(                                                      \
        (const __attribute__((address_space(1))) void*)(blsrc1 + (size_t)(kt) * 4096),     \
        (__attribute__((address_space(3))) void*)&BlS[buf][idx1 * 512], 16, 0, 0);         \
  } while (0)

  STG(0, 0);

#pragma unroll
  for (int kt = 0; kt < NKT; ++kt) {
    const int S = kt & 1;
    __syncthreads();  // drains stage(kt), issued one MFMA block earlier
    s16x8 afh[2], afl[2];
#pragma unroll
    for (int m = 0; m < 2; ++m) {
      int row = wr * 32 + m * 16 + l15;
      int swr = row & 7;
      float4 a0 = *(const float4*)&AfS[S][row * 32 + (((2 * l4) ^ swr) << 2)];
      float4 a1 = *(const float4*)&AfS[S][row * 32 + (((2 * l4 + 1) ^ swr) << 2)];
      cvt8(a0, a1, afh[m], afl[m]);
    }
    s16x8 bh[4], bl[4];
#pragma unroll
    for (int n = 0; n < 4; ++n) {
      int c = wc * 64 + n * 16 + l15;
      int q = l4 ^ ((c & 3) ^ ((c >> 2) & 3));
      bh[n] = *(const s16x8*)&BhS[S][c * 32 + q * 8];
      bl[n] = *(const s16x8*)&BlS[S][c * 32 + q * 8];
    }
    if (kt + 1 < NKT) STG(S ^ 1, kt + 1);
#pragma unroll
    for (int m = 0; m < 2; ++m)
#pragma unroll
      for (int n = 0; n < 4; ++n) {
        acc[m][n] = __builtin_amdgcn_mfma_f32_16x16x32_bf16(afh[m], bh[n], acc[m][n], 0, 0, 0);
        acc[m][n] = __builtin_amdgcn_mfma_f32_16x16x32_bf16(afl[m], bh[n], acc[m][n], 0, 0, 0);
        acc[m][n] = __builtin_amdgcn_mfma_f32_16x16x32_bf16(afh[m], bl[n], acc[m][n], 0, 0, 0);
      }
  }
#undef STG

#pragma unroll
  for (int m = 0; m < 2; ++m) {
    int rbase = brow + wr * 32 + m * 16 + l4 * 4;
#pragma unroll
    for (int n = 0; n < 4; ++n) {
      int c = wc * 64 + n * 16 + l15;
#pragma unroll
      for (int j = 0; j < 4; ++j) {
        int r = rbase + j;
        if (r < M) C[(size_t)r * 128 + c] = acc[m][n][j];
      }
    }
  }
}

// ---------------- MFMA split-bf16 GEMM (conv2): C[M][64] = A[M][128] @ B ----------------

static __global__ __launch_bounds__(256, 2) void k_gemm_mfma64(
    const float* __restrict__ A, const unsigned short* __restrict__ Bh,
    const unsigned short* __restrict__ Bl, float* __restrict__ C, int M) {
  int tid = threadIdx.x;
  int lane = tid & 63, wid = tid >> 6;
  int wr = wid >> 1, wc = wid & 1;
  int l15 = lane & 15, l4 = lane >> 4;
  int brow = blockIdx.x * 64;
  f32x4 acc[2][2] = {};

  const float* arow[2];
#pragma unroll
  for (int m = 0; m < 2; ++m) {
    int r = brow + wr * 32 + m * 16 + l15;
    arow[m] = &A[(size_t)min(r, M - 1) * 128 + l4 * 8];
  }
  size_t boff = (size_t)(wc * 32 + l15) * 32 + l4 * 8;

#pragma unroll
  for (int kt = 0; kt < 4; ++kt) {
    s16x8 afh[2], afl[2];
#pragma unroll
    for (int m = 0; m < 2; ++m) {
      float4 a0 = *(const float4*)(arow[m] + kt * 32);
      float4 a1 = *(const float4*)(arow[m] + kt * 32 + 4);
      cvt8(a0, a1, afh[m], afl[m]);
    }
    s16x8 bh[2], bl[2];
#pragma unroll
    for (int n = 0; n < 2; ++n) {
      size_t o = (size_t)kt * 2048 + boff + n * 512;
      bh[n] = *(const s16x8*)&Bh[o];
      bl[n] = *(const s16x8*)&Bl[o];
    }
#pragma unroll
    for (int m = 0; m < 2; ++m)
#pragma unroll
      for (int n = 0; n < 2; ++n) {
        acc[m][n] = __builtin_amdgcn_mfma_f32_16x16x32_bf16(afh[m], bh[n], acc[m][n], 0, 0, 0);
        acc[m][n] = __builtin_amdgcn_mfma_f32_16x16x32_bf16(afl[m], bh[n], acc[m][n], 0, 0, 0);
        acc[m][n] = __builtin_amdgcn_mfma_f32_16x16x32_bf16(afh[m], bl[n], acc[m][n], 0, 0, 0);
      }
  }

#pragma unroll
  for (int m = 0; m < 2; ++m) {
    int rbase = brow + wr * 32 + m * 16 + l4 * 4;
#pragma unroll
    for (int n = 0; n < 2; ++n) {
      int c = wc * 32 + n * 16 + l15;
#pragma unroll
      for (int j = 0; j < 4; ++j) {
        int r = rbase + j;
        if (r < M) C[(size_t)r * 64 + c] = acc[m][n][j];
      }
    }
  }
}

// ---------------- gather-aggregate (CSR with folded weights) ----------------

template <int F, bool RELU>
static __global__ __launch_bounds__(256) void k_gather4(
    const float* __restrict__ H, const int* __restrict__ rowptr,
    const int2* __restrict__ srcw, const float* __restrict__ dinv,
    const float* __restrict__ Hpre, const float* __restrict__ bias,
    float* __restrict__ out, int n) {
  const int L = F / 4;
  int node = blockIdx.x * (256 / L) + threadIdx.x / L;
  if (node >= n) return;
  int f4 = (threadIdx.x % L) * 4;
  float d = dinv[node];
  float4 hp = *(const float4*)&Hpre[(size_t)node * F + f4];
  float ax = hp.x * d, ay = hp.y * d, az = hp.z * d, aw = hp.w * d;
  int j = rowptr[node], e = rowptr[node + 1];
  for (; j + 1 < e; j += 2) {
    int2 a = srcw[j], b = srcw[j + 1];
    float w0 = __int_as_float(a.y);
    float w1 = __int_as_float(b.y);
    float4 v0 = *(const float4*)&H[(size_t)a.x * F + f4];
    float4 v1 = *(const float4*)&H[(size_t)b.x * F + f4];
    ax += v0.x * w0 + v1.x * w1;
    ay += v0.y * w0 + v1.y * w1;
    az += v0.z * w0 + v1.z * w1;
    aw += v0.w * w0 + v1.w * w1;
  }
  if (j < e) {
    int2 a = srcw[j];
    float wj = __int_as_float(a.y);
    float4 v = *(const float4*)&H[(size_t)a.x * F + f4];
    ax += v.x * wj; ay += v.y * wj; az += v.z * wj; aw += v.w * wj;
  }
  float bx = 0, by = 0, bz = 0, bw = 0;
  if (bias) { float4 bb = *(const float4*)&bias[f4]; bx = bb.x; by = bb.y; bz = bb.z; bw = bb.w; }
  ax = ax * d + bx; ay = ay * d + by; az = az * d + bz; aw = aw * d + bw;
  if (RELU) { ax = fmaxf(ax, 0.f); ay = fmaxf(ay, 0.f); az = fmaxf(az, 0.f); aw = fmaxf(aw, 0.f); }
  float4 o; o.x = ax; o.y = ay; o.z = az; o.w = aw;
  *(float4*)&out[(size_t)node * F + f4] = o;
}

// ---------------- fused dual-head (64->40 x2) + log-softmax ----------------

static __global__ __launch_bounds__(256) void k_heads(
    const float* __restrict__ H, const float* __restrict__ Wattr,
    const float* __restrict__ battr, const float* __restrict__ Watt,
    const float* __restrict__ batt, float* __restrict__ out_attr,
    float* __restrict__ out_att, int n) {
  __shared__ float Hs[64][65];
  __shared__ float Ws[64][80];
  __shared__ float bs[80];
  __shared__ float Os[64][82];
  int tid = threadIdx.x;
  int node0 = blockIdx.x * 64;
  for (int i = tid; i < 1024; i += 256) {
    int r = i >> 4, c4 = (i & 15) * 4;
    float4 v = (node0 + r < n) ? *(const float4*)&H[(size_t)(node0 + r) * 64 + c4]
                               : make_float4(0.f, 0.f, 0.f, 0.f);
    Hs[r][c4] = v.x; Hs[r][c4 + 1] = v.y; Hs[r][c4 + 2] = v.z; Hs[r][c4 + 3] = v.w;
  }
  for (int i = tid; i < 64 * 40; i += 256) {
    int k = i / 40, j = i - k * 40;
    Ws[k][j] = Wattr[i];
    Ws[k][40 + j] = Watt[i];
  }
  if (tid < 40) { bs[tid] = battr[tid]; bs[40 + tid] = batt[tid]; }
  __syncthreads();

  int r = tid & 63, g = tid >> 6;
  float acc[20];
#pragma unroll
  for (int j = 0; j < 20; ++j) acc[j] = bs[g * 20 + j];
  for (int k = 0; k < 64; ++k) {
    float h = Hs[r][k];
#pragma unroll
    for (int j = 0; j < 20; ++j) acc[j] += h * Ws[k][g * 20 + j];
  }
#pragma unroll
  for (int j = 0; j < 20; ++j) Os[r][g * 20 + j] = acc[j];
  __syncthreads();

  if (tid < 128 && node0 + (tid & 63) < n) {
    int r2 = tid & 63;
    int base = (tid >> 6) * 40;
    float m = -1e30f;
    for (int j = 0; j < 40; ++j) m = fmaxf(m, Os[r2][base + j]);
    float s = 0.f;
    for (int j = 0; j < 40; ++j) s += expf(Os[r2][base + j] - m);
    float ls = logf(s) + m;
    float* o = (tid < 64 ? out_attr : out_att) + (size_t)(node0 + r2) * 40;
    for (int j = 0; j < 40; ++j) o[j] = Os[r2][base + j] - ls;
  }
}

// ---------------- link prediction ----------------

static __global__ __launch_bounds__(256) void k_linkpred4(
    const float* __restrict__ H2, const int* __restrict__ pos,
    const int* __restrict__ neg, float* __restrict__ res, int Elp) {
  int t = blockIdx.x * 256 + threadIdx.x;
  int e = t >> 4, f4 = (t & 15) * 4;
  if (e >= 2 * Elp) return;
  int a, b;
  if (e < Elp) { a = pos[e]; b = pos[Elp + e]; }
  else { int e2 = e - Elp; a = neg[e2]; b = neg[Elp + e2]; }
  float4 va = *(const float4*)&H2[(size_t)a * 64 + f4];
  float4 vb = *(const float4*)&H2[(size_t)b * 64 + f4];
  float p = va.x * vb.x + va.y * vb.y + va.z * vb.z + va.w * vb.w;
  p += __shfl_xor(p, 1);
  p += __shfl_xor(p, 2);
  p += __shfl_xor(p, 4);
  p += __shfl_xor(p, 8);
  if ((t & 15) == 0) res[e] = p;
}

// ---------------- launch ----------------

extern "C" void kernel_launch(void* const* d_in, const int* in_sizes, int n_in,
                              void* d_out, int out_size, void* d_ws, size_t ws_size,
                              hipStream_t stream) {
  const float* x    = (const float*)d_in[0];
  const int*   tp   = (const int*)d_in[1];
  const int*   ei   = (const int*)d_in[2];
  const float* ew   = (const float*)d_in[3];
  const int*   pos  = (const int*)d_in[4];
  const int*   neg  = (const int*)d_in[5];
  const float* W1   = (const float*)d_in[6];
  const float* b1   = (const float*)d_in[7];
  const float* W2   = (const float*)d_in[8];
  const float* b2   = (const float*)d_in[9];
  const float* Wattr= (const float*)d_in[10];
  const float* battr= (const float*)d_in[11];
  const float* Watt = (const float*)d_in[12];
  const float* batt = (const float*)d_in[13];

  const int N   = in_sizes[0] / 512;  // 50000
  const int EMP = in_sizes[1] / 2;    // 800000
  const int ELP = in_sizes[4] / 2;    // 250000
  const int NB  = (N + 1023) / 1024;  // scan blocks per array
  const int NG  = (N + 63) / 64;      // gemm blocks

  // workspace layout (4B units, 16B-aligned regions)
  float* ws = (float*)d_ws;
  float* dinvT = ws;                          // N
  float* dinvE = dinvT + N;                   // N
  int* rowptrT = (int*)(dinvE + N);           // N+1 (+pad)
  int* rowptrE = rowptrT + (N + 4);           // N+1 (+pad)
  int2* srcwT  = (int2*)(rowptrE + (N + 4));  // EMP int2
  int2* srcwE  = srcwT + EMP;                 // EMP int2
  int* bsum    = (int*)(srcwE + EMP);         // 2*NB (+pad)
  unsigned short* W1h = (unsigned short*)(bsum + 128);  // 512*128 bf16 (k-tiled, swizzled)
  unsigned short* W1l = W1h + 512 * 128;
  unsigned short* W2h = W1l + 512 * 128;      // 128*64 bf16 (k-tiled, linear)
  unsigned short* W2l = W2h + 128 * 64;
  float* bufA  = (float*)(W2l + 128 * 64);    // N*128
  float* bufB  = bufA + (size_t)N * 128;      // N*128
  float* bufC  = bufB + (size_t)N * 128;      // N*64
  // ranks: DEDICATED region (concurrent with gemm writing bufA — no overlay!)
  int* rankT = (int*)(bufC + (size_t)N * 64); // EMP
  int* rankE = rankT + EMP;                   // EMP
  // overlays (dead before their hosts are written):
  int* cntTp = (int*)bufB;                    // N*CPAD padded counters
  int* cntEp = cntTp + (size_t)N * CPAD;      // N*CPAD
  int* cntT  = cntEp + (size_t)N * CPAD;      // N dense
  int* cntE  = cntT + N;                      // N dense

  float* out_res  = (float*)d_out;
  float* out_attr = out_res + 2 * (size_t)ELP;
  float* out_att  = out_attr + (size_t)N * 40;

  dim3 b256(256);
  int gN = (N + 255) / 256;
  int gE2 = (EMP + 511) / 512;

  // counters zero + W converts (all precede the fused kernel)
  k_init<<<gN, b256, 0, stream>>>(cntTp, cntEp, N);
  k_cvtW<<<(512 * 128 + 255) / 256, b256, 0, stream>>>(W1, W1h, W1l, 512, 128, 1);
  k_cvtW<<<(128 * 64 + 255) / 256, b256, 0, stream>>>(W2, W2h, W2l, 128, 64, 0);

  // FUSED: conv1 GEMM (h1_pre = x @ W1) + k_count (interleaved blocks)
  k_gemm_count<<<NG * 5, b256, 0, stream>>>(x, W1h, W1l, bufA, N, NG,
                                            tp + EMP, ei + EMP, cntTp, cntEp,
                                            rankT, rankE, EMP);

  // CSR build rest
  k_compact<<<gN, b256, 0, stream>>>(cntTp, cntEp, cntT, cntE, N);
  k_dinvT<<<gN, b256, 0, stream>>>(cntT, dinvT, N);
  {
    dim3 gs(NB, 2);
    k_scanA<<<gs, b256, 0, stream>>>(cntT, cntE, bsum, N, NB);
    k_scanB<<<1, 64, 0, stream>>>(bsum, rowptrT, rowptrE, NB, N);
    k_scanC<<<gs, b256, 0, stream>>>(cntT, cntE, bsum, rowptrT, rowptrE, N, NB);
  }
  k_fill<<<gE2, b256, 0, stream>>>(tp, tp + EMP, ei, ei + EMP, ew, dinvT,
                                   rowptrT, rowptrE, rankT, rankE, srcwT, srcwE, EMP);
  k_dinv2E<<<gN, b256, 0, stream>>>(srcwE, rowptrE, dinvE, N);
  k_wmulE<<<(EMP + 511) / 512, b256, 0, stream>>>(srcwE, dinvE, EMP);

  // conv1 aggregate: h = relu(Agg_T(h1_pre) + b1)
  k_gather4<128, true><<<(N + 7) / 8, b256, 0, stream>>>(
      bufA, rowptrT, srcwT, dinvT, bufA, b1, bufB, N);

  // conv2: h2_pre = h @ W2 ; h2 = Agg_T(h2_pre) + b2
  k_gemm_mfma64<<<(N + 63) / 64, b256, 0, stream>>>(bufB, W2h, W2l, bufA, N);
  k_gather4<64, false><<<(N + 15) / 16, b256, 0, stream>>>(
      bufA, rowptrT, srcwT, dinvT, bufA, b2, bufC, N);

  // conv3/4 share aggregation: agg3 = Agg_E(h2) into bufA
  k_gather4<64, false><<<(N + 15) / 16, b256, 0, stream>>>(
      bufC, rowptrE, srcwE, dinvE, bufC, nullptr, bufA, N);

  // fused heads + log-softmax
  k_heads<<<(N + 63) / 64, b256, 0, stream>>>(
      bufA, Wattr, battr, Watt, batt, out_attr, out_att, N);

  // link prediction (h2 = bufC)
  k_linkpred4<<<(2 * ELP * 16 + 255) / 256, b256, 0, stream>>>(bufC, pos, neg, out_res, ELP);
}